// Round 1
// baseline (1180.336 us; speedup 1.0000x reference)
//
#include <hip/hip_runtime.h>
#include <math.h>

#define BB 64
#define SS 4096
#define AA 4
#define LL 64
#define DD 300
#define WIN 60
#define WSTRIDE 5
#define NW 808
#define AL (AA*LL)      // 256
#define NUNITS (BB*AA)  // 256

// workspace layout (float offsets)
#define OFF_AN  0                         // a_n: [B][AL][D] = 4,915,200 floats
#define OFF_INV 4915200                   // inv_s: [B][S]   =   262,144 floats
#define OFF_AVG 5177344                   // avg: [B][A][NW] =   206,848 floats
#define OFF_SC  5384192                   // score slices: [S][L] per unit = 262,144 floats
#define SLICE_FLOATS (SS*LL)
#define FIXED_BYTES (OFF_SC * 4)

__global__ __launch_bounds__(256) void k_norm_a(const float* __restrict__ la,
                                                float* __restrict__ an) {
    int row = blockIdx.x * 4 + (threadIdx.x >> 6);
    int lane = threadIdx.x & 63;
    if (row >= BB * AL) return;
    const float* src = la + (size_t)row * DD;
    float ss = 0.f;
    for (int i = lane; i < DD; i += 64) { float v = src[i]; ss += v * v; }
    for (int off = 32; off; off >>= 1) ss += __shfl_xor(ss, off);
    float inv = 1.0f / sqrtf(ss + 1e-6f);
    float* dst = an + (size_t)row * DD;
    for (int i = lane; i < DD; i += 64) dst[i] = src[i] * inv;
}

__global__ __launch_bounds__(256) void k_inv_s(const float* __restrict__ ls,
                                               float* __restrict__ inv) {
    int row = blockIdx.x * 4 + (threadIdx.x >> 6);
    int lane = threadIdx.x & 63;
    if (row >= BB * SS) return;
    const float* src = ls + (size_t)row * DD;
    float ss = 0.f;
    for (int i = lane; i < DD; i += 64) { float v = src[i]; ss += v * v; }
    for (int off = 32; off; off >>= 1) ss += __shfl_xor(ss, off);
    if (lane == 0) inv[row] = 1.0f / sqrtf(ss + 1e-6f);
}

#define BK 60
__global__ __launch_bounds__(256) void k_gemm(const float* __restrict__ ls,
                                              const float* __restrict__ an,
                                              const float* __restrict__ inv,
                                              float* __restrict__ sc, int u0) {
    int unit = u0 + blockIdx.y;
    int b = unit >> 2, a = unit & 3;
    int s0 = blockIdx.x * 64;
    __shared__ float As[BK][68];
    __shared__ float Bs[BK][68];
    float acc[4][4] = {};
    int tid = threadIdx.x;
    int tx = tid & 15, ty = tid >> 4;
    const float* Abase = ls + ((size_t)b * SS + s0) * DD;
    const float* Bbase = an + ((size_t)b * AL + a * LL) * DD;
    const float* invb = inv + b * SS + s0;
    for (int k0 = 0; k0 < DD; k0 += BK) {
        for (int idx = tid; idx < 960; idx += 256) {
            int r = idx / 15, c = idx % 15;
            float4 v = *(const float4*)(Abase + (size_t)r * DD + k0 + c * 4);
            float iv = invb[r];
            As[c*4+0][r] = v.x * iv;
            As[c*4+1][r] = v.y * iv;
            As[c*4+2][r] = v.z * iv;
            As[c*4+3][r] = v.w * iv;
            float4 w = *(const float4*)(Bbase + (size_t)r * DD + k0 + c * 4);
            Bs[c*4+0][r] = w.x;
            Bs[c*4+1][r] = w.y;
            Bs[c*4+2][r] = w.z;
            Bs[c*4+3][r] = w.w;
        }
        __syncthreads();
        #pragma unroll
        for (int k = 0; k < BK; ++k) {
            float4 av = *(const float4*)&As[k][ty * 4];
            float4 bv = *(const float4*)&Bs[k][tx * 4];
            float aa[4] = {av.x, av.y, av.z, av.w};
            float bb[4] = {bv.x, bv.y, bv.z, bv.w};
            #pragma unroll
            for (int i = 0; i < 4; ++i)
                #pragma unroll
                for (int j = 0; j < 4; ++j)
                    acc[i][j] += aa[i] * bb[j];
        }
        __syncthreads();
    }
    float* out = sc + (size_t)blockIdx.y * SLICE_FLOATS + (size_t)s0 * LL;
    #pragma unroll
    for (int i = 0; i < 4; ++i) {
        float4 v = {acc[i][0], acc[i][1], acc[i][2], acc[i][3]};
        *(float4*)(out + (size_t)(ty * 4 + i) * LL + tx * 4) = v;
    }
}

// 16 windows per chunk -> 51 chunks over 808 windows; slab span = 5*15+60 = 135 rows
__global__ __launch_bounds__(256) void k_pool(const float* __restrict__ sc,
                                              const float* __restrict__ g,
                                              float* __restrict__ avg, int u0) {
    int unit = u0 + blockIdx.y;
    int b = unit >> 2, a = unit & 3;
    int nw0 = blockIdx.x * 16;
    int nwc = min(16, NW - nw0);
    int s0 = nw0 * WSTRIDE;
    int span = min(WSTRIDE * (nwc - 1) + WIN, SS - s0);
    __shared__ float scs[135 * 64];
    __shared__ float gw[WIN];
    int tid = threadIdx.x;
    if (tid < WIN) gw[tid] = g[tid];
    const float* src = sc + (size_t)blockIdx.y * SLICE_FLOATS + (size_t)s0 * LL;
    for (int idx = tid; idx < span * 64; idx += 256) scs[idx] = src[idx];
    __syncthreads();
    int wv = tid >> 6, lane = tid & 63;
    for (int j = wv; j < nwc; j += 4) {
        float pooled = -INFINITY;
        int base = j * WSTRIDE * 64 + lane;
        #pragma unroll
        for (int w = 0; w < WIN; ++w)
            pooled = fmaxf(pooled, gw[w] * scs[base + w * 64]);
        float sum = pooled;
        float cnt = (pooled != 0.0f) ? 1.0f : 0.0f;
        for (int off = 32; off; off >>= 1) {
            sum += __shfl_xor(sum, off);
            cnt += __shfl_xor(cnt, off);
        }
        if (lane == 0)
            avg[((size_t)b * AA + a) * NW + nw0 + j] = sum / (cnt + 1e-5f);
    }
}

__global__ __launch_bounds__(256) void k_reduce(const float* __restrict__ avg,
                                                const float* __restrict__ alpha_p,
                                                float* __restrict__ out) {
    int ba = blockIdx.x;
    const float* src = avg + (size_t)ba * NW;
    int tid = threadIdx.x;
    float m = -INFINITY;
    for (int i = tid; i < NW; i += 256) m = fmaxf(m, src[i]);
    __shared__ float red[256];
    red[tid] = m;
    __syncthreads();
    for (int s = 128; s; s >>= 1) {
        if (tid < s) red[tid] = fmaxf(red[tid], red[tid + s]);
        __syncthreads();
    }
    if (tid == 0) out[ba] = red[0] * alpha_p[0];
}

extern "C" void kernel_launch(void* const* d_in, const int* in_sizes, int n_in,
                              void* d_out, int out_size, void* d_ws, size_t ws_size,
                              hipStream_t stream) {
    const float* ls    = (const float*)d_in[0];  // [B,S,D]
    const float* la    = (const float*)d_in[1];  // [B,A,L,D]
    const float* alpha = (const float*)d_in[2];  // scalar
    const float* g     = (const float*)d_in[3];  // [60]
    float* out = (float*)d_out;
    float* ws  = (float*)d_ws;

    float* an  = ws + OFF_AN;
    float* inv = ws + OFF_INV;
    float* avg = ws + OFF_AVG;
    float* sc  = ws + OFF_SC;

    size_t avail = ws_size > (size_t)FIXED_BYTES ? ws_size - FIXED_BYTES : 0;
    int NU = (int)(avail / ((size_t)SLICE_FLOATS * 4));
    if (NU < 1) NU = 1;
    if (NU > NUNITS) NU = NUNITS;

    k_norm_a<<<(BB * AL) / 4, 256, 0, stream>>>(la, an);
    k_inv_s<<<(BB * SS) / 4, 256, 0, stream>>>(ls, inv);
    for (int u0 = 0; u0 < NUNITS; u0 += NU) {
        int nu = (NU < NUNITS - u0) ? NU : (NUNITS - u0);
        k_gemm<<<dim3(64, nu), 256, 0, stream>>>(ls, an, inv, sc, u0);
        k_pool<<<dim3(51, nu), 256, 0, stream>>>(sc, g, avg, u0);
    }
    k_reduce<<<NUNITS, 256, 0, stream>>>(avg, alpha, out);
}

// Round 2
// 668.114 us; speedup vs baseline: 1.7667x; 1.7667x over previous
//
#include <hip/hip_runtime.h>
#include <math.h>

#define BB 64
#define SS 4096
#define AA 4
#define LL 64
#define DD 300
#define DPAD 320
#define WIN 60
#define WSTRIDE 5
#define NW 808
#define AL (AA*LL)      // 256

typedef __attribute__((ext_vector_type(8))) short short8;
typedef __attribute__((ext_vector_type(4))) float f32x4;

// ---- workspace layout (bytes) ----
// Bp2: bf16 [64][256][320]            = 10,485,760
// avg: f32  [64][4][808]              =    827,392
// per b-group: Ap bf16 [gb][4096][320] (2,621,440/b) + sc f32 [gb][4][4096][64] (4,194,304/b)
#define OFF_AVG   10485760
#define OFF_DYN   11313152
#define PERB_AP   2621440
#define PERB_SC   4194304
#define SLICE     (SS*LL)   // floats per (b,a) score slice

static __device__ inline ushort f2bf(float x) {
    union { float f; uint u; } v; v.f = x;
    uint r = v.u + 0x7fff + ((v.u >> 16) & 1);
    return (ushort)(r >> 16);
}

// normalize rows of length 300 (f32) -> bf16 rows padded to 320 with zeros
__global__ __launch_bounds__(256) void k_prep(const float* __restrict__ src,
                                              ushort* __restrict__ dst,
                                              int nrows) {
    int row = blockIdx.x * 4 + (threadIdx.x >> 6);
    int lane = threadIdx.x & 63;
    if (row >= nrows) return;
    const float* s = src + (size_t)row * DD;
    float4 v0 = {0.f,0.f,0.f,0.f}, v1 = {0.f,0.f,0.f,0.f};
    if (lane < 75) v0 = *(const float4*)(s + 4 * lane);
    if (lane < 11) v1 = *(const float4*)(s + 4 * (lane + 64));
    float ss = v0.x*v0.x + v0.y*v0.y + v0.z*v0.z + v0.w*v0.w
             + v1.x*v1.x + v1.y*v1.y + v1.z*v1.z + v1.w*v1.w;
    for (int off = 32; off; off >>= 1) ss += __shfl_xor(ss, off);
    float inv = 1.0f / sqrtf(ss + 1e-6f);
    ushort* d = dst + (size_t)row * DPAD;
    if (lane < 75) {
        ushort4 o; o.x=f2bf(v0.x*inv); o.y=f2bf(v0.y*inv); o.z=f2bf(v0.z*inv); o.w=f2bf(v0.w*inv);
        *(ushort4*)(d + 4 * lane) = o;
    }
    if (lane < 11) {
        ushort4 o; o.x=f2bf(v1.x*inv); o.y=f2bf(v1.y*inv); o.z=f2bf(v1.z*inv); o.w=f2bf(v1.w*inv);
        *(ushort4*)(d + 4 * (lane + 64)) = o;
    } else if (lane < 16) {  // pad slots 75..79 (k = 300..319) with zeros
        ushort4 z = {0,0,0,0};
        *(ushort4*)(d + 4 * (lane + 64)) = z;
    }
}

static __device__ inline void glds16(const ushort* g, ushort* l) {
    __builtin_amdgcn_global_load_lds(
        (const __attribute__((address_space(1))) void*)g,
        (__attribute__((address_space(3))) void*)l, 16, 0, 0);
}

// C[4096x256] = A[4096x320]bf16 * B^T[256x320]bf16, per b. BM=128, BK=32.
// Wave w owns cols [64w,64w+64) == answer a=w. sc layout: [gb][4][4096][64] f32.
__global__ __launch_bounds__(256, 2) void k_gemm(const ushort* __restrict__ Ap,
                                                 const ushort* __restrict__ Bp,
                                                 float* __restrict__ sc,
                                                 int b0) {
    __shared__ ushort lds[2][4096 + 8192];  // A 128x32, B 256x32 per buffer (48KB)
    int bl = blockIdx.y;
    int b  = b0 + bl;
    int s0 = blockIdx.x * 128;
    int tid = threadIdx.x;
    int w = tid >> 6, lane = tid & 63;
    int g = lane >> 4, r16 = lane & 15;
    const ushort* Ab = Ap + ((size_t)bl * SS + s0) * DPAD;
    const ushort* Bb = Bp + (size_t)b * AL * DPAD;

    f32x4 acc[8][4] = {};

    auto stage = [&](int buf, int k0) {
        ushort* lA = &lds[buf][0];
        ushort* lB = &lds[buf][4096];
        #pragma unroll
        for (int j = 0; j < 2; ++j) {           // A tile: 512 quads of 16B
            int q = j * 256 + tid;
            int row = q >> 2, x = q & 3;
            int kq = x ^ ((row >> 1) & 3);      // pre-swizzled source -> swizzled LDS
            glds16(Ab + (size_t)row * DPAD + k0 + kq * 8, lA + (j * 256 + w * 64) * 8);
        }
        #pragma unroll
        for (int j = 0; j < 4; ++j) {           // B tile: 1024 quads
            int q = j * 256 + tid;
            int col = q >> 2, x = q & 3;
            int kq = x ^ ((col >> 1) & 3);
            glds16(Bb + (size_t)col * DPAD + k0 + kq * 8, lB + (j * 256 + w * 64) * 8);
        }
    };

    stage(0, 0);
    __syncthreads();
    int cur = 0;
    for (int step = 0; step < 10; ++step) {
        if (step < 9) stage(cur ^ 1, (step + 1) * 32);
        const ushort* Abuf = &lds[cur][0];
        const ushort* Bbuf = &lds[cur][4096];
        short8 Af[8], Bf[4];
        #pragma unroll
        for (int m = 0; m < 8; ++m) {
            int row = m * 16 + r16;
            int kq = g ^ ((row >> 1) & 3);
            Af[m] = *(const short8*)(Abuf + row * 32 + kq * 8);
        }
        #pragma unroll
        for (int n = 0; n < 4; ++n) {
            int col = w * 64 + n * 16 + r16;
            int kq = g ^ ((col >> 1) & 3);
            Bf[n] = *(const short8*)(Bbuf + col * 32 + kq * 8);
        }
        #pragma unroll
        for (int m = 0; m < 8; ++m)
            #pragma unroll
            for (int n = 0; n < 4; ++n)
                acc[m][n] = __builtin_amdgcn_mfma_f32_16x16x32_bf16(Af[m], Bf[n], acc[m][n], 0, 0, 0);
        __syncthreads();
        cur ^= 1;
    }

    float* out = sc + (((size_t)bl * AA + w) * SS + s0) * LL;
    #pragma unroll
    for (int m = 0; m < 8; ++m)
        #pragma unroll
        for (int n = 0; n < 4; ++n) {
            int col = n * 16 + r16;
            int rowb = m * 16 + g * 4;
            #pragma unroll
            for (int r = 0; r < 4; ++r)
                out[(size_t)(rowb + r) * LL + col] = acc[m][n][r];
        }
}

// 16 windows/chunk, slab span <= 135 rows of 64 cols
__global__ __launch_bounds__(256) void k_pool(const float* __restrict__ sc,
                                              const float* __restrict__ g,
                                              float* __restrict__ avg, int b0) {
    int unit = blockIdx.y;                  // local: bl*4 + a
    int b = b0 + (unit >> 2), a = unit & 3;
    int nw0 = blockIdx.x * 16;
    int nwc = min(16, NW - nw0);
    int s0 = nw0 * WSTRIDE;
    int span = min(WSTRIDE * (nwc - 1) + WIN, SS - s0);
    __shared__ float scs[135 * 64];
    __shared__ float gw[WIN];
    int tid = threadIdx.x;
    if (tid < WIN) gw[tid] = g[tid];
    const float* src = sc + (size_t)unit * SLICE + (size_t)s0 * LL;
    for (int idx = tid; idx < span * 16; idx += 256)
        ((float4*)scs)[idx] = ((const float4*)src)[idx];
    __syncthreads();
    int wv = tid >> 6, lane = tid & 63;
    for (int j = wv; j < nwc; j += 4) {
        float pooled = -INFINITY;
        int base = j * WSTRIDE * 64 + lane;
        #pragma unroll
        for (int w = 0; w < WIN; ++w)
            pooled = fmaxf(pooled, gw[w] * scs[base + w * 64]);
        float sum = pooled;
        float cnt = (pooled != 0.0f) ? 1.0f : 0.0f;
        for (int off = 32; off; off >>= 1) {
            sum += __shfl_xor(sum, off);
            cnt += __shfl_xor(cnt, off);
        }
        if (lane == 0)
            avg[((size_t)b * AA + a) * NW + nw0 + j] = sum / (cnt + 1e-5f);
    }
}

__global__ __launch_bounds__(256) void k_reduce(const float* __restrict__ avg,
                                                const float* __restrict__ alpha_p,
                                                float* __restrict__ out) {
    int ba = blockIdx.x;
    const float* src = avg + (size_t)ba * NW;
    int tid = threadIdx.x;
    float m = -INFINITY;
    for (int i = tid; i < NW; i += 256) m = fmaxf(m, src[i]);
    __shared__ float red[256];
    red[tid] = m;
    __syncthreads();
    for (int s = 128; s; s >>= 1) {
        if (tid < s) red[tid] = fmaxf(red[tid], red[tid + s]);
        __syncthreads();
    }
    if (tid == 0) out[ba] = red[0] * alpha_p[0];
}

extern "C" void kernel_launch(void* const* d_in, const int* in_sizes, int n_in,
                              void* d_out, int out_size, void* d_ws, size_t ws_size,
                              hipStream_t stream) {
    const float* ls    = (const float*)d_in[0];
    const float* la    = (const float*)d_in[1];
    const float* alpha = (const float*)d_in[2];
    const float* g     = (const float*)d_in[3];
    float* out = (float*)d_out;
    char* ws = (char*)d_ws;

    ushort* Bp2 = (ushort*)ws;
    float*  avg = (float*)(ws + OFF_AVG);
    char*   dyn = ws + OFF_DYN;

    size_t perb = (size_t)PERB_AP + PERB_SC;
    size_t avail = ws_size > (size_t)OFF_DYN ? ws_size - OFF_DYN : 0;
    int Gb = (int)(avail / perb);
    if (Gb < 1) Gb = 1;
    if (Gb > BB) Gb = BB;

    k_prep<<<(BB * AL) / 4, 256, 0, stream>>>(la, Bp2, BB * AL);
    for (int b0 = 0; b0 < BB; b0 += Gb) {
        int gb = (Gb < BB - b0) ? Gb : (BB - b0);
        ushort* Ap = (ushort*)dyn;
        float*  sc = (float*)(dyn + (size_t)Gb * PERB_AP);
        k_prep<<<(gb * SS) / 4, 256, 0, stream>>>(ls + (size_t)b0 * SS * DD, Ap, gb * SS);
        k_gemm<<<dim3(SS / 128, gb), 256, 0, stream>>>(Ap, Bp2, sc, b0);
        k_pool<<<dim3(51, gb * 4), 256, 0, stream>>>(sc, g, avg, b0);
    }
    k_reduce<<<BB * AA, 256, 0, stream>>>(avg, alpha, out);
}